// Round 9
// baseline (228.193 us; speedup 1.0000x reference)
//
#include <hip/hip_runtime.h>
#include <hip/hip_fp16.h>
#include <stdint.h>

#define M_DIM 64
#define K_DIM 8192
#define N_DIM 28672
#define QGROUP 128

typedef __attribute__((ext_vector_type(4))) float floatx4;
typedef __attribute__((ext_vector_type(8))) _Float16 halfx8;
typedef __attribute__((ext_vector_type(4))) uint32_t uintx4;

template <typename T, typename F>
__device__ __forceinline__ T bc(F f) {
  static_assert(sizeof(T) == sizeof(F), "size mismatch");
  T t;
  __builtin_memcpy(&t, &f, sizeof(T));
  return t;
}

// p = two fp16 lanes holding (1024+nib); returns two fp16 of (nib-8)*s
__device__ __forceinline__ uint32_t dq_pair(uint32_t p, uint32_t s2bits) {
  __half2 v = bc<__half2>(p);
  __half2 z = bc<__half2>(0x64086408u);  // (1032, 1032)
  __half2 s = bc<__half2>(s2bits);
  return bc<uint32_t>(__hmul2(__hsub2(v, z), s));
}

// one packed dword -> 8 fp16 in PERMUTED k-order [0,4,1,5,2,6,3,7]
__device__ __forceinline__ halfx8 dequant8(uint32_t q, uint32_t s2bits) {
  const uint32_t MM = 0x000F000Fu;
  const uint32_t MG = 0x64006400u;
  uintx4 r;
  r.x = dq_pair((q & MM) | MG, s2bits);
  r.y = dq_pair(((q >> 4) & MM) | MG, s2bits);
  r.z = dq_pair(((q >> 8) & MM) | MG, s2bits);
  r.w = dq_pair(((q >> 12) & MM) | MG, s2bits);
  return bc<halfx8>(r);
}

// A (fp32) -> fragment-ordered fp16 pack with the same k-permutation.
// Apack[((t*4+mf)*64 + l)*8 + j] = (f16)A[(l&15)+16*mf][32*t + 8*(l>>4) + perm[j]]
__global__ __launch_bounds__(256) void pack_a(const float* __restrict__ A,
                                              _Float16* __restrict__ Apack) {
  const int g = (int)blockIdx.x * 256 + (int)threadIdx.x;
  const int l = g & 63;
  const int mf = (g >> 6) & 3;
  const int t = g >> 8;
  const int row = (l & 15) + 16 * mf;
  const int k0 = 32 * t + 8 * (l >> 4);
  const float* src = A + (size_t)row * K_DIM + k0;
  floatx4 a0 = *(const floatx4*)src;
  floatx4 a1 = *(const floatx4*)(src + 4);
  halfx8 hv;
  hv[0] = (_Float16)a0[0]; hv[1] = (_Float16)a1[0];
  hv[2] = (_Float16)a0[1]; hv[3] = (_Float16)a1[1];
  hv[4] = (_Float16)a0[2]; hv[5] = (_Float16)a1[2];
  hv[6] = (_Float16)a0[3]; hv[7] = (_Float16)a1[3];
  *(halfx8*)(Apack + (size_t)g * 8) = hv;
}

// global -> LDS DMA, 16B per lane; lds base must be wave-uniform.
__device__ __forceinline__ void stage16(const _Float16* gsrc, _Float16* lds) {
  __builtin_amdgcn_global_load_lds(
      (const __attribute__((address_space(1))) uint32_t*)gsrc,
      (__attribute__((address_space(3))) uint32_t*)lds, 16, 0, 0);
}

// ===== r6's PASSING kernel, byte-identical body (do not edit: the vmcnt
// cadence is the verified-correct one; r7/r8's "equivalent" cadences both
// corrupted A tiles). 4-wave block (256 thr), block tile 64m x 512n,
// per-wave 64m x 128n. A staged per block per 32-K step (4 KB) via
// global_load_lds into a 4-deep LDS ring, 2 steps ahead; q prefetched 4
// steps deep in compile-time slots; counted vmcnt(3) + raw s_barrier per
// step. THIS ROUND: only the launch geometry changes (KSPLIT=16 -> 896
// blocks = 3.5 blocks/CU = 14 waves/CU) to test the TLP hypothesis.
template <int KSLICE, bool SPLIT>
__global__ __launch_bounds__(256, 2) void wq_lds(
    const _Float16* __restrict__ Apack, // fragment-ordered fp16
    const int* __restrict__ qweight,    // int32, K/8 x N
    const float* __restrict__ scales,   // fp32, K/128 x N (fp16-exact)
    const float* __restrict__ bias,     // fp32, N (fp16-exact)
    float* __restrict__ part,           // KSPLIT x M x N (fp32)
    float* __restrict__ out) {          // fp32, M x N
  constexpr int STEPS = KSLICE / 32;
  constexpr int GROUPS = KSLICE / QGROUP;
  __shared__ __align__(16) _Float16 Abuf[4][2048];  // 4 x 4KB ring

  const int tid = (int)threadIdx.x;
  const int w = tid >> 6;
  const int l = tid & 63;
  const int l15 = l & 15;
  const int l4 = l >> 4;
  const int nbW = (int)blockIdx.x * 512 + w * 128;
  const int kb = (int)blockIdx.y * KSLICE;
  const int ncol = nbW + 4 * l15;

  const int* qptr = qweight + (size_t)((kb >> 3) + l4) * N_DIM + ncol;
  const float* sptr = scales + (size_t)(kb / QGROUP) * N_DIM + ncol;
  const _Float16* asrc = Apack + (size_t)(kb >> 5) * 2048 + tid * 8;
  _Float16* const ldsw = &Abuf[0][0] + w * 512;  // wave's quarter (uniform)

  floatx4 acc[4][8];
#pragma unroll
  for (int i = 0; i < 4; ++i)
#pragma unroll
    for (int j = 0; j < 8; ++j) acc[i][j] = (floatx4)(0.0f);

  // ---- prologue: q_0..q_3 (slots 0..3), scales g0, stage steps 0,1; then
  // ONE full drain + barrier establishes clean vmcnt cadence ----
  uintx4 qa[4], qb[4];
#pragma unroll
  for (int s = 0; s < 4; ++s) {
    qa[s] = *(const uintx4*)qptr;
    qb[s] = *(const uintx4*)(qptr + 64);
    qptr += 4 * (size_t)N_DIM;  // -> step s+1 rows; ends at step 4
  }
  floatx4 scv0 = *(const floatx4*)sptr;
  floatx4 scv1 = *(const floatx4*)(sptr + 64);
  sptr += N_DIM;
  stage16(asrc, ldsw);          // step 0 -> buf0
  asrc += 2048;
  stage16(asrc, ldsw + 2048);   // step 1 -> buf1
  asrc += 2048;
  __syncthreads();              // vmcnt(0)+lgkmcnt(0)+barrier, once

  floatx4 scn0 = scv0, scn1 = scv1;

  for (int g = 0; g < GROUPS; ++g) {
    uint32_t s2b[8];
#pragma unroll
    for (int d = 0; d < 4; ++d) {
      unsigned short sb0 = bc<unsigned short>((_Float16)scv0[d]);
      uint32_t u0 = (uint32_t)sb0;
      s2b[d] = u0 | (u0 << 16);
      unsigned short sb1 = bc<unsigned short>((_Float16)scv1[d]);
      uint32_t u1 = (uint32_t)sb1;
      s2b[4 + d] = u1 | (u1 << 16);
    }
#pragma unroll
    for (int tt = 0; tt < 4; ++tt) {
      const int t = g * 4 + tt;  // buf index = t&3 = tt (compile-time)
      // Counted wait: retire stage_t (issued 2 iters ago; >=3 newer vmem
      // ops follow it by pinned order) WITHOUT draining q_{t+1..t+3} /
      // stage_{t+1}. Then barrier: all waves' stage_t parts landed.
      asm volatile("s_waitcnt vmcnt(3)" ::: "memory");
      __builtin_amdgcn_s_barrier();
      __builtin_amdgcn_sched_barrier(0);
      // A fragments: conflict-free ds_read_b128 (lanes consecutive 16B)
      halfx8 afr[4];
#pragma unroll
      for (int mf = 0; mf < 4; ++mf)
        afr[mf] = *(const halfx8*)&Abuf[tt][mf * 512 + l * 8];
      // compute: 8 dequant columns x 4 m-fragments = 32 MFMA
#pragma unroll
      for (int d = 0; d < 4; ++d) {
        halfx8 b = dequant8(qa[tt][d], s2b[d]);
#pragma unroll
        for (int mf = 0; mf < 4; ++mf)
          acc[mf][d] = __builtin_amdgcn_mfma_f32_16x16x32_f16(afr[mf], b,
                                                              acc[mf][d], 0, 0, 0);
      }
#pragma unroll
      for (int d = 0; d < 4; ++d) {
        halfx8 b = dequant8(qb[tt][d], s2b[4 + d]);
#pragma unroll
        for (int mf = 0; mf < 4; ++mf)
          acc[mf][4 + d] = __builtin_amdgcn_mfma_f32_16x16x32_f16(afr[mf], b,
                                                                  acc[mf][4 + d], 0, 0, 0);
      }
      __builtin_amdgcn_sched_barrier(0);
      // stage step t+2 into buf[(tt+2)&3] (clamped address at the tail so
      // the vmcnt cadence stays exact; stale stages are never read)
      stage16(asrc, ldsw + ((tt + 2) & 3) * 2048);
      asrc += (t + 3 < STEPS) ? 2048 : 0;
      __builtin_amdgcn_sched_barrier(0);  // pin: stage before q
      // q for step t+4 into slot tt (consumed above -> no WAR copies)
      qa[tt] = *(const uintx4*)qptr;
      qb[tt] = *(const uintx4*)(qptr + 64);
      qptr += (t + 5 < STEPS) ? 4 * (size_t)N_DIM : (size_t)0;
      if (tt == 0) {  // scales for group g+1 (3-iter cover, clamped)
        scn0 = *(const floatx4*)sptr;
        scn1 = *(const floatx4*)(sptr + 64);
        sptr += (g + 1 < GROUPS) ? N_DIM : 0;
      }
      __builtin_amdgcn_sched_barrier(0);
    }
    scv0 = scn0;
    scv1 = scn1;
  }

  // Epilogue. row = 4*l4 + r (+16*mf), col = l&15; fragment d at (mf,r,h)
  // covers n = nbW + 64*h + 4*(l&15) + d -> 4 consecutive n.
  if (SPLIT) {
    float* pbase = part + (size_t)blockIdx.y * ((size_t)M_DIM * N_DIM);
#pragma unroll
    for (int h = 0; h < 2; ++h) {
      const int nc = ncol + 64 * h;
#pragma unroll
      for (int mf = 0; mf < 4; ++mf) {
#pragma unroll
        for (int r = 0; r < 4; ++r) {
          const int m = mf * 16 + l4 * 4 + r;
          floatx4 v = {acc[mf][4 * h + 0][r], acc[mf][4 * h + 1][r],
                       acc[mf][4 * h + 2][r], acc[mf][4 * h + 3][r]};
          *(floatx4*)(pbase + (size_t)m * N_DIM + nc) = v;
        }
      }
    }
  } else {
#pragma unroll
    for (int h = 0; h < 2; ++h) {
      const int nc = ncol + 64 * h;
      floatx4 bb = *(const floatx4*)(bias + nc);
#pragma unroll
      for (int mf = 0; mf < 4; ++mf) {
#pragma unroll
        for (int r = 0; r < 4; ++r) {
          const int m = mf * 16 + l4 * 4 + r;
          floatx4 v = {acc[mf][4 * h + 0][r] + bb.x, acc[mf][4 * h + 1][r] + bb.y,
                       acc[mf][4 * h + 2][r] + bb.z, acc[mf][4 * h + 3][r] + bb.w};
          *(floatx4*)(out + (size_t)m * N_DIM + nc) = v;
        }
      }
    }
  }
}

// Fallback (no workspace): r5's register kernel, raw fp32 A, full K, 1 wave.
__global__ __launch_bounds__(64, 2) void wq_reg(
    const float* __restrict__ A, const int* __restrict__ qweight,
    const float* __restrict__ scales, const float* __restrict__ bias,
    float* __restrict__ out) {
  constexpr int KSLICE = K_DIM;
  constexpr int STEPS = KSLICE / 32;
  constexpr int GROUPS = KSLICE / QGROUP;
  const int l = (int)threadIdx.x & 63;
  const int l15 = l & 15;
  const int l4 = l >> 4;
  const int nb = (int)blockIdx.x * 128;
  const int ncol = nb + 4 * l15;
  const int* qptr = qweight + (size_t)l4 * N_DIM + ncol;
  const float* sptr = scales + ncol;
  const float* araw = A + (size_t)l15 * K_DIM + 8 * l4;

  floatx4 acc[4][8];
#pragma unroll
  for (int i = 0; i < 4; ++i)
#pragma unroll
    for (int j = 0; j < 8; ++j) acc[i][j] = (floatx4)(0.0f);

  uintx4 q0a = *(const uintx4*)qptr;
  uintx4 q0b = *(const uintx4*)(qptr + 64);
  qptr += 4 * (size_t)N_DIM;
  uintx4 q1a = *(const uintx4*)qptr;
  uintx4 q1b = *(const uintx4*)(qptr + 64);
  qptr += 4 * (size_t)N_DIM;
  floatx4 scv0 = *(const floatx4*)sptr;
  floatx4 scv1 = *(const floatx4*)(sptr + 64);
  sptr += N_DIM;

  for (int g = 0; g < GROUPS; ++g) {
    uint32_t s2b[8];
#pragma unroll
    for (int d = 0; d < 4; ++d) {
      unsigned short sb0 = bc<unsigned short>((_Float16)scv0[d]);
      uint32_t u0 = (uint32_t)sb0;
      s2b[d] = u0 | (u0 << 16);
      unsigned short sb1 = bc<unsigned short>((_Float16)scv1[d]);
      uint32_t u1 = (uint32_t)sb1;
      s2b[4 + d] = u1 | (u1 << 16);
    }
    floatx4 scn0 = scv0, scn1 = scv1;
    if (g + 1 < GROUPS) {
      scn0 = *(const floatx4*)sptr;
      scn1 = *(const floatx4*)(sptr + 64);
    }
    sptr += N_DIM;
#pragma unroll
    for (int tt = 0; tt < 4; ++tt) {
      const int t = g * 4 + tt;
      halfx8 afr[4];
#pragma unroll
      for (int mf = 0; mf < 4; ++mf) {
        const float* s0 = araw + (size_t)mf * 16 * K_DIM + (size_t)t * 32;
        floatx4 a0 = *(const floatx4*)s0;
        floatx4 a1 = *(const floatx4*)(s0 + 4);
        afr[mf][0] = (_Float16)a0[0]; afr[mf][1] = (_Float16)a1[0];
        afr[mf][2] = (_Float16)a0[1]; afr[mf][3] = (_Float16)a1[1];
        afr[mf][4] = (_Float16)a0[2]; afr[mf][5] = (_Float16)a1[2];
        afr[mf][6] = (_Float16)a0[3]; afr[mf][7] = (_Float16)a1[3];
      }
      uintx4 qna = q1a, qnb = q1b;
      if (t + 2 < STEPS) {
        qna = *(const uintx4*)qptr;
        qnb = *(const uintx4*)(qptr + 64);
      }
      qptr += 4 * (size_t)N_DIM;
#pragma unroll
      for (int d = 0; d < 4; ++d) {
        halfx8 b = dequant8(q0a[d], s2b[d]);
#pragma unroll
        for (int mf = 0; mf < 4; ++mf)
          acc[mf][d] = __builtin_amdgcn_mfma_f32_16x16x32_f16(afr[mf], b,
                                                              acc[mf][d], 0, 0, 0);
      }
#pragma unroll
      for (int d = 0; d < 4; ++d) {
        halfx8 b = dequant8(q0b[d], s2b[4 + d]);
#pragma unroll
        for (int mf = 0; mf < 4; ++mf)
          acc[mf][4 + d] = __builtin_amdgcn_mfma_f32_16x16x32_f16(afr[mf], b,
                                                                  acc[mf][4 + d], 0, 0, 0);
      }
      q0a = q1a; q0b = q1b;
      q1a = qna; q1b = qnb;
    }
    scv0 = scn0;
    scv1 = scn1;
  }
#pragma unroll
  for (int h = 0; h < 2; ++h) {
    const int nc = ncol + 64 * h;
    floatx4 bb = *(const floatx4*)(bias + nc);
#pragma unroll
    for (int mf = 0; mf < 4; ++mf) {
#pragma unroll
      for (int r = 0; r < 4; ++r) {
        const int m = mf * 16 + l4 * 4 + r;
        floatx4 v = {acc[mf][4 * h + 0][r] + bb.x, acc[mf][4 * h + 1][r] + bb.y,
                     acc[mf][4 * h + 2][r] + bb.z, acc[mf][4 * h + 3][r] + bb.w};
        *(floatx4*)(out + (size_t)m * N_DIM + nc) = v;
      }
    }
  }
}

// Sum KS fp32 partials, add fp32 bias, emit fp32.
template <int KS>
__global__ __launch_bounds__(256) void wq_reduce(const float* __restrict__ part,
                                                 const float* __restrict__ bias,
                                                 float* __restrict__ out) {
  const int idx = (int)blockIdx.x * 256 + (int)threadIdx.x;
  const int m = idx / (N_DIM / 4);
  const int n = (idx - m * (N_DIM / 4)) * 4;
  floatx4 s = (floatx4)(0.0f);
#pragma unroll
  for (int p = 0; p < KS; ++p)
    s += *(const floatx4*)(part + ((size_t)p * M_DIM + m) * N_DIM + n);
  floatx4 bb = *(const floatx4*)(bias + n);
  s += bb;
  *(floatx4*)(out + (size_t)m * N_DIM + n) = s;
}

extern "C" void kernel_launch(void* const* d_in, const int* in_sizes, int n_in,
                              void* d_out, int out_size, void* d_ws, size_t ws_size,
                              hipStream_t stream) {
  const float* A = (const float*)d_in[0];
  const int* qw = (const int*)d_in[1];
  const float* sc = (const float*)d_in[2];
  const float* bi = (const float*)d_in[3];
  float* out = (float*)d_out;

  char* ws = (char*)d_ws;
  const size_t packB = (size_t)M_DIM * K_DIM * sizeof(_Float16);  // 1 MiB
  const size_t mnB = (size_t)M_DIM * N_DIM * sizeof(float);       // 7.34 MB
  _Float16* Apack = (_Float16*)ws;
  float* part = (float*)(ws + packB);

  const int nblk = N_DIM / 512;                // 56 (4-wave 512n blocks)
  const int rblk = (M_DIM * N_DIM / 4) / 256;  // 1792

  if (ws_size >= packB + 16 * mnB) {
    // (56, 16) = 896 blocks x 4 waves = 3584 waves = 14 waves/CU
    pack_a<<<256, 256, 0, stream>>>(A, Apack);
    wq_lds<K_DIM / 16, true><<<dim3(nblk, 16), 256, 0, stream>>>(
        Apack, qw, sc, bi, part, out);
    wq_reduce<16><<<rblk, 256, 0, stream>>>(part, bi, out);
  } else if (ws_size >= packB + 8 * mnB) {
    // (56, 8) = 448 blocks = 7 waves/CU (r6's passing config)
    pack_a<<<256, 256, 0, stream>>>(A, Apack);
    wq_lds<K_DIM / 8, true><<<dim3(nblk, 8), 256, 0, stream>>>(
        Apack, qw, sc, bi, part, out);
    wq_reduce<8><<<rblk, 256, 0, stream>>>(part, bi, out);
  } else if (ws_size >= packB + 4 * mnB) {
    pack_a<<<256, 256, 0, stream>>>(A, Apack);
    wq_lds<K_DIM / 4, true><<<dim3(nblk, 4), 256, 0, stream>>>(
        Apack, qw, sc, bi, part, out);
    wq_reduce<4><<<rblk, 256, 0, stream>>>(part, bi, out);
  } else if (ws_size >= packB + 2 * mnB) {
    pack_a<<<256, 256, 0, stream>>>(A, Apack);
    wq_lds<K_DIM / 2, true><<<dim3(nblk, 2), 256, 0, stream>>>(
        Apack, qw, sc, bi, part, out);
    wq_reduce<2><<<rblk, 256, 0, stream>>>(part, bi, out);
  } else if (ws_size >= packB) {
    pack_a<<<256, 256, 0, stream>>>(A, Apack);
    wq_lds<K_DIM, false><<<dim3(nblk, 1), 256, 0, stream>>>(
        Apack, qw, sc, bi, part, out);
  } else {
    wq_reg<<<dim3(N_DIM / 128, 1), 64, 0, stream>>>(A, qw, sc, bi, out);
  }
}

// Round 11
// 208.493 us; speedup vs baseline: 1.0945x; 1.0945x over previous
//
#include <hip/hip_runtime.h>
#include <hip/hip_fp16.h>
#include <stdint.h>

#define M_DIM 64
#define K_DIM 8192
#define N_DIM 28672
#define QGROUP 128

typedef __attribute__((ext_vector_type(4))) float floatx4;
typedef __attribute__((ext_vector_type(8))) _Float16 halfx8;
typedef __attribute__((ext_vector_type(4))) uint32_t uintx4;

template <typename T, typename F>
__device__ __forceinline__ T bc(F f) {
  static_assert(sizeof(T) == sizeof(F), "size mismatch");
  T t;
  __builtin_memcpy(&t, &f, sizeof(T));
  return t;
}

// p = two fp16 lanes holding (1024+nib); returns two fp16 of (nib-8)*s
__device__ __forceinline__ uint32_t dq_pair(uint32_t p, uint32_t s2bits) {
  __half2 v = bc<__half2>(p);
  __half2 z = bc<__half2>(0x64086408u);  // (1032, 1032)
  __half2 s = bc<__half2>(s2bits);
  return bc<uint32_t>(__hmul2(__hsub2(v, z), s));
}

// one packed dword -> 8 fp16 in PERMUTED k-order [0,4,1,5,2,6,3,7]
__device__ __forceinline__ halfx8 dequant8(uint32_t q, uint32_t s2bits) {
  const uint32_t MM = 0x000F000Fu;
  const uint32_t MG = 0x64006400u;
  uintx4 r;
  r.x = dq_pair((q & MM) | MG, s2bits);
  r.y = dq_pair(((q >> 4) & MM) | MG, s2bits);
  r.z = dq_pair(((q >> 8) & MM) | MG, s2bits);
  r.w = dq_pair(((q >> 12) & MM) | MG, s2bits);
  return bc<halfx8>(r);
}

// A (fp32) -> fragment-ordered fp16 pack with the same k-permutation.
// Apack[((t*4+mf)*64 + l)*8 + j] = (f16)A[(l&15)+16*mf][32*t + 8*(l>>4) + perm[j]]
__global__ __launch_bounds__(256) void pack_a(const float* __restrict__ A,
                                              _Float16* __restrict__ Apack) {
  const int g = (int)blockIdx.x * 256 + (int)threadIdx.x;
  const int l = g & 63;
  const int mf = (g >> 6) & 3;
  const int t = g >> 8;
  const int row = (l & 15) + 16 * mf;
  const int k0 = 32 * t + 8 * (l >> 4);
  const float* src = A + (size_t)row * K_DIM + k0;
  floatx4 a0 = *(const floatx4*)src;
  floatx4 a1 = *(const floatx4*)(src + 4);
  halfx8 hv;
  hv[0] = (_Float16)a0[0]; hv[1] = (_Float16)a1[0];
  hv[2] = (_Float16)a0[1]; hv[3] = (_Float16)a1[1];
  hv[4] = (_Float16)a0[2]; hv[5] = (_Float16)a1[2];
  hv[6] = (_Float16)a0[3]; hv[7] = (_Float16)a1[3];
  *(halfx8*)(Apack + (size_t)g * 8) = hv;
}

// global -> LDS DMA, 16B per lane; lds base must be wave-uniform.
__device__ __forceinline__ void stage16(const _Float16* gsrc, _Float16* lds) {
  __builtin_amdgcn_global_load_lds(
      (const __attribute__((address_space(1))) uint32_t*)gsrc,
      (__attribute__((address_space(3))) uint32_t*)lds, 16, 0, 0);
}

// ===== WAVE-PRIVATE STAGING, ZERO BARRIERS =====
// Lesson from r7/r8/r10 (3 corruption failures): counted-vmcnt with
// CROSS-WAVE LDS consumption is fragile — any hidden vmem op shifts the
// positional count and one-position errors corrupt other waves' reads.
// Here each wave stages its OWN full 4KB A-tile (4x stage16) into its own
// LDS double-buffer and reads only that. No cross-wave hazard exists, so
// there are NO barriers. The per-iter wait is vmcnt(2), and the only ops
// ever allowed to remain in flight are the 2 NEWEST (next-step q pair):
// every stage op is followed by >=2 younger ops (pinned), so unexpected
// extra vmem ops (scratch etc.) can only make the wait MORE conservative
// (perf loss), never leave a stage unretired (corruption-impossible).
// 4-wave block (256 thr), block tile 64m x 512n, per-wave 64m x 128n.
// LDS: 4 waves x 2 bufs x 4KB = 32KB. Grid (56, KSPLIT=8) = 448 blocks.
template <int KSLICE, bool SPLIT>
__global__ __launch_bounds__(256, 2) void wq_pvt(
    const _Float16* __restrict__ Apack, // fragment-ordered fp16
    const int* __restrict__ qweight,    // int32, K/8 x N
    const float* __restrict__ scales,   // fp32, K/128 x N (fp16-exact)
    const float* __restrict__ bias,     // fp32, N (fp16-exact)
    float* __restrict__ part,           // KSPLIT x M x N (fp32)
    float* __restrict__ out) {          // fp32, M x N
  constexpr int STEPS = KSLICE / 32;    // >= 32 in all tiers
  constexpr int GROUPS = KSLICE / QGROUP;
  __shared__ __align__(16) _Float16 Abuf[4][2][2048];  // [wave][buf][4KB]

  const int tid = (int)threadIdx.x;
  const int w = tid >> 6;
  const int l = tid & 63;
  const int l15 = l & 15;
  const int l4 = l >> 4;
  const int nbW = (int)blockIdx.x * 512 + w * 128;
  const int kb = (int)blockIdx.y * KSLICE;
  const int ncol = nbW + 4 * l15;

  const int* qptr = qweight + (size_t)((kb >> 3) + l4) * N_DIM + ncol;
  const float* sptr = scales + (size_t)(kb / QGROUP) * N_DIM + ncol;
  const _Float16* asrc = Apack + (size_t)(kb >> 5) * 2048 + l * 8;  // per-lane
  _Float16* const myb0 = &Abuf[w][0][0];  // wave-private (uniform base)
  _Float16* const myb1 = &Abuf[w][1][0];

  floatx4 acc[4][8];
#pragma unroll
  for (int i = 0; i < 4; ++i)
#pragma unroll
    for (int j = 0; j < 8; ++j) acc[i][j] = (floatx4)(0.0f);

  // ---- prologue (issue order pinned: S(0) x4, SC, Q(0), Q(1)) ----
#pragma unroll
  for (int c = 0; c < 4; ++c) stage16(asrc + c * 512, myb0 + c * 512);
  asrc += 2048;  // -> step 1
  __builtin_amdgcn_sched_barrier(0);
  floatx4 scv0 = *(const floatx4*)sptr;
  floatx4 scv1 = *(const floatx4*)(sptr + 64);
  sptr += N_DIM;
  __builtin_amdgcn_sched_barrier(0);
  uintx4 qa[2], qb[2];
  qa[0] = *(const uintx4*)qptr;
  qb[0] = *(const uintx4*)(qptr + 64);
  qptr += 4 * (size_t)N_DIM;
  qa[1] = *(const uintx4*)qptr;
  qb[1] = *(const uintx4*)(qptr + 64);
  qptr += 4 * (size_t)N_DIM;  // -> step 2
  __builtin_amdgcn_sched_barrier(0);

  floatx4 scn0 = scv0, scn1 = scv1;

  for (int g = 0; g < GROUPS; ++g) {
    uint32_t s2b[8];
#pragma unroll
    for (int d = 0; d < 4; ++d) {
      unsigned short sb0 = bc<unsigned short>((_Float16)scv0[d]);  // exact
      uint32_t u0 = (uint32_t)sb0;
      s2b[d] = u0 | (u0 << 16);  // fp16x2 splat
      unsigned short sb1 = bc<unsigned short>((_Float16)scv1[d]);
      uint32_t u1 = (uint32_t)sb1;
      s2b[4 + d] = u1 | (u1 << 16);
    }
#pragma unroll
    for (int tt = 0; tt < 4; ++tt) {
      const int j = g * 4 + tt;
      const int pb = tt & 1;   // parity of j (g*4 even) — compile-time
      // Wait: everything except the 2 newest (the q(j+1)...q pair issued
      // last iter) must retire — in particular this iter's S(j) stages.
      // Robust: S(j) is ALWAYS followed by >=2 younger ops.
      asm volatile("s_waitcnt vmcnt(2)" ::: "memory");
      __builtin_amdgcn_sched_barrier(0);
      // A fragments from OWN buffer: conflict-free ds_read_b128
      const _Float16* rb = pb ? myb1 : myb0;
      halfx8 afr[4];
#pragma unroll
      for (int mf = 0; mf < 4; ++mf)
        afr[mf] = *(const halfx8*)(rb + mf * 512 + l * 8);
      // compute: 8 dequant columns x 4 m-fragments = 32 MFMA
#pragma unroll
      for (int d = 0; d < 4; ++d) {
        halfx8 b = dequant8(qa[pb][d], s2b[d]);
#pragma unroll
        for (int mf = 0; mf < 4; ++mf)
          acc[mf][d] = __builtin_amdgcn_mfma_f32_16x16x32_f16(afr[mf], b,
                                                              acc[mf][d], 0, 0, 0);
      }
#pragma unroll
      for (int d = 0; d < 4; ++d) {
        halfx8 b = dequant8(qb[pb][d], s2b[4 + d]);
#pragma unroll
        for (int mf = 0; mf < 4; ++mf)
          acc[mf][4 + d] = __builtin_amdgcn_mfma_f32_16x16x32_f16(afr[mf], b,
                                                                  acc[mf][4 + d], 0, 0, 0);
      }
      __builtin_amdgcn_sched_barrier(0);
      // stage S(j+1) into the other private buffer (read next iter after
      // vmcnt(2); at the tail the address is clamped — restaged data is
      // never read)
      _Float16* wb = pb ? myb0 : myb1;
#pragma unroll
      for (int c = 0; c < 4; ++c) stage16(asrc + c * 512, wb + c * 512);
      asrc += (j + 2 < STEPS) ? 2048 : 0;
      if (tt == 0) {  // scales for group g+1 (issued before q -> q stays newest)
        __builtin_amdgcn_sched_barrier(0);
        scn0 = *(const floatx4*)sptr;
        scn1 = *(const floatx4*)(sptr + 64);
        sptr += (g + 1 < GROUPS) ? N_DIM : 0;
      }
      __builtin_amdgcn_sched_barrier(0);
      // q for step j+2 into just-consumed slot (clamped at tail; count kept)
      qa[pb] = *(const uintx4*)qptr;
      qb[pb] = *(const uintx4*)(qptr + 64);
      qptr += (j + 3 < STEPS) ? 4 * (size_t)N_DIM : (size_t)0;
      __builtin_amdgcn_sched_barrier(0);
    }
    scv0 = scn0;
    scv1 = scn1;
  }

  // Epilogue. row = 4*l4 + r (+16*mf); fragment d at (mf,r,h) covers
  // n = nbW + 64*h + 4*(l&15) + d -> 4 consecutive n. FP32 partials (proven).
  if (SPLIT) {
    float* pbase = part + (size_t)blockIdx.y * ((size_t)M_DIM * N_DIM);
#pragma unroll
    for (int h = 0; h < 2; ++h) {
      const int nc = ncol + 64 * h;
#pragma unroll
      for (int mf = 0; mf < 4; ++mf) {
#pragma unroll
        for (int r = 0; r < 4; ++r) {
          const int m = mf * 16 + l4 * 4 + r;
          floatx4 v = {acc[mf][4 * h + 0][r], acc[mf][4 * h + 1][r],
                       acc[mf][4 * h + 2][r], acc[mf][4 * h + 3][r]};
          *(floatx4*)(pbase + (size_t)m * N_DIM + nc) = v;
        }
      }
    }
  } else {
#pragma unroll
    for (int h = 0; h < 2; ++h) {
      const int nc = ncol + 64 * h;
      floatx4 bb = *(const floatx4*)(bias + nc);
#pragma unroll
      for (int mf = 0; mf < 4; ++mf) {
#pragma unroll
        for (int r = 0; r < 4; ++r) {
          const int m = mf * 16 + l4 * 4 + r;
          floatx4 v = {acc[mf][4 * h + 0][r] + bb.x, acc[mf][4 * h + 1][r] + bb.y,
                       acc[mf][4 * h + 2][r] + bb.z, acc[mf][4 * h + 3][r] + bb.w};
          *(floatx4*)(out + (size_t)m * N_DIM + nc) = v;
        }
      }
    }
  }
}

// Fallback (no workspace): register kernel, raw fp32 A, full K, 1 wave.
__global__ __launch_bounds__(64, 2) void wq_reg(
    const float* __restrict__ A, const int* __restrict__ qweight,
    const float* __restrict__ scales, const float* __restrict__ bias,
    float* __restrict__ out) {
  constexpr int KSLICE = K_DIM;
  constexpr int STEPS = KSLICE / 32;
  constexpr int GROUPS = KSLICE / QGROUP;
  const int l = (int)threadIdx.x & 63;
  const int l15 = l & 15;
  const int l4 = l >> 4;
  const int nb = (int)blockIdx.x * 128;
  const int ncol = nb + 4 * l15;
  const int* qptr = qweight + (size_t)l4 * N_DIM + ncol;
  const float* sptr = scales + ncol;
  const float* araw = A + (size_t)l15 * K_DIM + 8 * l4;

  floatx4 acc[4][8];
#pragma unroll
  for (int i = 0; i < 4; ++i)
#pragma unroll
    for (int j = 0; j < 8; ++j) acc[i][j] = (floatx4)(0.0f);

  uintx4 q0a = *(const uintx4*)qptr;
  uintx4 q0b = *(const uintx4*)(qptr + 64);
  qptr += 4 * (size_t)N_DIM;
  uintx4 q1a = *(const uintx4*)qptr;
  uintx4 q1b = *(const uintx4*)(qptr + 64);
  qptr += 4 * (size_t)N_DIM;
  floatx4 scv0 = *(const floatx4*)sptr;
  floatx4 scv1 = *(const floatx4*)(sptr + 64);
  sptr += N_DIM;

  for (int g = 0; g < GROUPS; ++g) {
    uint32_t s2b[8];
#pragma unroll
    for (int d = 0; d < 4; ++d) {
      unsigned short sb0 = bc<unsigned short>((_Float16)scv0[d]);
      uint32_t u0 = (uint32_t)sb0;
      s2b[d] = u0 | (u0 << 16);
      unsigned short sb1 = bc<unsigned short>((_Float16)scv1[d]);
      uint32_t u1 = (uint32_t)sb1;
      s2b[4 + d] = u1 | (u1 << 16);
    }
    floatx4 scn0 = scv0, scn1 = scv1;
    if (g + 1 < GROUPS) {
      scn0 = *(const floatx4*)sptr;
      scn1 = *(const floatx4*)(sptr + 64);
    }
    sptr += N_DIM;
#pragma unroll
    for (int tt = 0; tt < 4; ++tt) {
      const int t = g * 4 + tt;
      halfx8 afr[4];
#pragma unroll
      for (int mf = 0; mf < 4; ++mf) {
        const float* s0 = araw + (size_t)mf * 16 * K_DIM + (size_t)t * 32;
        floatx4 a0 = *(const floatx4*)s0;
        floatx4 a1 = *(const floatx4*)(s0 + 4);
        afr[mf][0] = (_Float16)a0[0]; afr[mf][1] = (_Float16)a1[0];
        afr[mf][2] = (_Float16)a0[1]; afr[mf][3] = (_Float16)a1[1];
        afr[mf][4] = (_Float16)a0[2]; afr[mf][5] = (_Float16)a1[2];
        afr[mf][6] = (_Float16)a0[3]; afr[mf][7] = (_Float16)a1[3];
      }
      uintx4 qna = q1a, qnb = q1b;
      if (t + 2 < STEPS) {
        qna = *(const uintx4*)qptr;
        qnb = *(const uintx4*)(qptr + 64);
      }
      qptr += 4 * (size_t)N_DIM;
#pragma unroll
      for (int d = 0; d < 4; ++d) {
        halfx8 b = dequant8(q0a[d], s2b[d]);
#pragma unroll
        for (int mf = 0; mf < 4; ++mf)
          acc[mf][d] = __builtin_amdgcn_mfma_f32_16x16x32_f16(afr[mf], b,
                                                              acc[mf][d], 0, 0, 0);
      }
#pragma unroll
      for (int d = 0; d < 4; ++d) {
        halfx8 b = dequant8(q0b[d], s2b[4 + d]);
#pragma unroll
        for (int mf = 0; mf < 4; ++mf)
          acc[mf][4 + d] = __builtin_amdgcn_mfma_f32_16x16x32_f16(afr[mf], b,
                                                                  acc[mf][4 + d], 0, 0, 0);
      }
      q0a = q1a; q0b = q1b;
      q1a = qna; q1b = qnb;
    }
    scv0 = scn0;
    scv1 = scn1;
  }
#pragma unroll
  for (int h = 0; h < 2; ++h) {
    const int nc = ncol + 64 * h;
    floatx4 bb = *(const floatx4*)(bias + nc);
#pragma unroll
    for (int mf = 0; mf < 4; ++mf) {
#pragma unroll
      for (int r = 0; r < 4; ++r) {
        const int m = mf * 16 + l4 * 4 + r;
        floatx4 v = {acc[mf][4 * h + 0][r] + bb.x, acc[mf][4 * h + 1][r] + bb.y,
                     acc[mf][4 * h + 2][r] + bb.z, acc[mf][4 * h + 3][r] + bb.w};
        *(floatx4*)(out + (size_t)m * N_DIM + nc) = v;
      }
    }
  }
}

// Sum KS fp32 partials, add fp32 bias, emit fp32.
template <int KS>
__global__ __launch_bounds__(256) void wq_reduce(const float* __restrict__ part,
                                                 const float* __restrict__ bias,
                                                 float* __restrict__ out) {
  const int idx = (int)blockIdx.x * 256 + (int)threadIdx.x;
  const int m = idx / (N_DIM / 4);
  const int n = (idx - m * (N_DIM / 4)) * 4;
  floatx4 s = (floatx4)(0.0f);
#pragma unroll
  for (int p = 0; p < KS; ++p)
    s += *(const floatx4*)(part + ((size_t)p * M_DIM + m) * N_DIM + n);
  floatx4 bb = *(const floatx4*)(bias + n);
  s += bb;
  *(floatx4*)(out + (size_t)m * N_DIM + n) = s;
}

extern "C" void kernel_launch(void* const* d_in, const int* in_sizes, int n_in,
                              void* d_out, int out_size, void* d_ws, size_t ws_size,
                              hipStream_t stream) {
  const float* A = (const float*)d_in[0];
  const int* qw = (const int*)d_in[1];
  const float* sc = (const float*)d_in[2];
  const float* bi = (const float*)d_in[3];
  float* out = (float*)d_out;

  char* ws = (char*)d_ws;
  const size_t packB = (size_t)M_DIM * K_DIM * sizeof(_Float16);  // 1 MiB
  const size_t mnB = (size_t)M_DIM * N_DIM * sizeof(float);       // 7.34 MB
  _Float16* Apack = (_Float16*)ws;
  float* part = (float*)(ws + packB);

  const int nblk = N_DIM / 512;                // 56 (4-wave 512n blocks)
  const int rblk = (M_DIM * N_DIM / 4) / 256;  // 1792

  if (ws_size >= packB + 8 * mnB) {
    // (56, 8) = 448 blocks x 4 waves = 1792 waves = 7 waves/CU nominal
    pack_a<<<256, 256, 0, stream>>>(A, Apack);
    wq_pvt<K_DIM / 8, true><<<dim3(nblk, 8), 256, 0, stream>>>(
        Apack, qw, sc, bi, part, out);
    wq_reduce<8><<<rblk, 256, 0, stream>>>(part, bi, out);
  } else if (ws_size >= packB + 4 * mnB) {
    pack_a<<<256, 256, 0, stream>>>(A, Apack);
    wq_pvt<K_DIM / 4, true><<<dim3(nblk, 4), 256, 0, stream>>>(
        Apack, qw, sc, bi, part, out);
    wq_reduce<4><<<rblk, 256, 0, stream>>>(part, bi, out);
  } else if (ws_size >= packB + 2 * mnB) {
    pack_a<<<256, 256, 0, stream>>>(A, Apack);
    wq_pvt<K_DIM / 2, true><<<dim3(nblk, 2), 256, 0, stream>>>(
        Apack, qw, sc, bi, part, out);
    wq_reduce<2><<<rblk, 256, 0, stream>>>(part, bi, out);
  } else if (ws_size >= packB) {
    pack_a<<<256, 256, 0, stream>>>(A, Apack);
    wq_pvt<K_DIM, false><<<dim3(nblk, 1), 256, 0, stream>>>(
        Apack, qw, sc, bi, part, out);
  } else {
    wq_reg<<<dim3(N_DIM / 128, 1), 64, 0, stream>>>(A, qw, sc, bi, out);
  }
}

// Round 13
// 208.064 us; speedup vs baseline: 1.0967x; 1.0021x over previous
//
#include <hip/hip_runtime.h>
#include <hip/hip_fp16.h>
#include <stdint.h>

#define M_DIM 64
#define K_DIM 8192
#define N_DIM 28672
#define QGROUP 128

typedef __attribute__((ext_vector_type(4))) float floatx4;
typedef __attribute__((ext_vector_type(8))) _Float16 halfx8;
typedef __attribute__((ext_vector_type(4))) uint32_t uintx4;

template <typename T, typename F>
__device__ __forceinline__ T bc(F f) {
  static_assert(sizeof(T) == sizeof(F), "size mismatch");
  T t;
  __builtin_memcpy(&t, &f, sizeof(T));
  return t;
}

// p = two fp16 lanes holding (1024+nib); returns two fp16 of (nib-8)*s
__device__ __forceinline__ uint32_t dq_pair(uint32_t p, uint32_t s2bits) {
  __half2 v = bc<__half2>(p);
  __half2 z = bc<__half2>(0x64086408u);  // (1032, 1032)
  __half2 s = bc<__half2>(s2bits);
  return bc<uint32_t>(__hmul2(__hsub2(v, z), s));
}

// one packed dword -> 8 fp16 in PERMUTED k-order [0,4,1,5,2,6,3,7]
__device__ __forceinline__ halfx8 dequant8(uint32_t q, uint32_t s2bits) {
  const uint32_t MM = 0x000F000Fu;
  const uint32_t MG = 0x64006400u;
  uintx4 r;
  r.x = dq_pair((q & MM) | MG, s2bits);
  r.y = dq_pair(((q >> 4) & MM) | MG, s2bits);
  r.z = dq_pair(((q >> 8) & MM) | MG, s2bits);
  r.w = dq_pair(((q >> 12) & MM) | MG, s2bits);
  return bc<halfx8>(r);
}

// A (fp32) -> fragment-ordered fp16 pack with the same k-permutation.
// Apack[((t*4+mf)*64 + l)*8 + j] = (f16)A[(l&15)+16*mf][32*t + 8*(l>>4) + perm[j]]
__global__ __launch_bounds__(256) void pack_a(const float* __restrict__ A,
                                              _Float16* __restrict__ Apack) {
  const int g = (int)blockIdx.x * 256 + (int)threadIdx.x;
  const int l = g & 63;
  const int mf = (g >> 6) & 3;
  const int t = g >> 8;
  const int row = (l & 15) + 16 * mf;
  const int k0 = 32 * t + 8 * (l >> 4);
  const float* src = A + (size_t)row * K_DIM + k0;
  floatx4 a0 = *(const floatx4*)src;
  floatx4 a1 = *(const floatx4*)(src + 4);
  halfx8 hv;
  hv[0] = (_Float16)a0[0]; hv[1] = (_Float16)a1[0];
  hv[2] = (_Float16)a0[1]; hv[3] = (_Float16)a1[1];
  hv[4] = (_Float16)a0[2]; hv[5] = (_Float16)a1[2];
  hv[6] = (_Float16)a0[3]; hv[7] = (_Float16)a1[3];
  *(halfx8*)(Apack + (size_t)g * 8) = hv;
}

// global -> LDS DMA, 16B per lane; lds base must be wave-uniform.
__device__ __forceinline__ void stage16(const _Float16* gsrc, _Float16* lds) {
  __builtin_amdgcn_global_load_lds(
      (const __attribute__((address_space(1))) uint32_t*)gsrc,
      (__attribute__((address_space(3))) uint32_t*)lds, 16, 0, 0);
}

// ===== WAVE-PRIVATE STAGING, ZERO BARRIERS (r11, VERIFIED) =====
// Final configuration. Empirical record of this session (12 rounds):
//  - counted-vmcnt with cross-wave LDS consumption corrupted 3 times
//    (r7/r8/r10) under source-level "equivalent" cadences -> positional
//    vmcnt counting across mixed global_load_lds + register loads is NOT
//    predictable from source on gfx950; r10 showed even epilogue-only
//    codegen perturbation can flip the r6 body's latent race.
//  - this wave-private variant is the only one that passed AND was
//    replay-stable: each wave stages its OWN 4KB A-tile into its own LDS
//    double-buffer and reads only that; no cross-wave hazard -> no
//    barriers; wait vmcnt(2) always has >=2 tracked ops younger than the
//    newest stage, so unexpected vmem ops only make it stricter.
//  - perf plateau: ~69.4 us for this kernel across five structurally
//    distinct implementations; VALUBusy<=27%, MfmaUtil<=17%, HBM<=28%,
//    conflicts 0 -> latency-bound; finer tiles / deeper KSPLIT either
//    corrupt (r7/r8/r12) or add traffic that cancels the gain (r9).
// 4-wave block (256 thr), block tile 64m x 512n, per-wave 64m x 128n.
// LDS: 4 waves x 2 bufs x 4KB = 32KB. Grid (56, KSPLIT=8) = 448 blocks.
template <int KSLICE, bool SPLIT>
__global__ __launch_bounds__(256, 2) void wq_pvt(
    const _Float16* __restrict__ Apack, // fragment-ordered fp16
    const int* __restrict__ qweight,    // int32, K/8 x N
    const float* __restrict__ scales,   // fp32, K/128 x N (fp16-exact)
    const float* __restrict__ bias,     // fp32, N (fp16-exact)
    float* __restrict__ part,           // KSPLIT x M x N (fp32)
    float* __restrict__ out) {          // fp32, M x N
  constexpr int STEPS = KSLICE / 32;    // >= 32 in all tiers
  constexpr int GROUPS = KSLICE / QGROUP;
  __shared__ __align__(16) _Float16 Abuf[4][2][2048];  // [wave][buf][4KB]

  const int tid = (int)threadIdx.x;
  const int w = tid >> 6;
  const int l = tid & 63;
  const int l15 = l & 15;
  const int l4 = l >> 4;
  const int nbW = (int)blockIdx.x * 512 + w * 128;
  const int kb = (int)blockIdx.y * KSLICE;
  const int ncol = nbW + 4 * l15;

  const int* qptr = qweight + (size_t)((kb >> 3) + l4) * N_DIM + ncol;
  const float* sptr = scales + (size_t)(kb / QGROUP) * N_DIM + ncol;
  const _Float16* asrc = Apack + (size_t)(kb >> 5) * 2048 + l * 8;  // per-lane
  _Float16* const myb0 = &Abuf[w][0][0];  // wave-private (uniform base)
  _Float16* const myb1 = &Abuf[w][1][0];

  floatx4 acc[4][8];
#pragma unroll
  for (int i = 0; i < 4; ++i)
#pragma unroll
    for (int j = 0; j < 8; ++j) acc[i][j] = (floatx4)(0.0f);

  // ---- prologue (issue order pinned: S(0) x4, SC, Q(0), Q(1)) ----
#pragma unroll
  for (int c = 0; c < 4; ++c) stage16(asrc + c * 512, myb0 + c * 512);
  asrc += 2048;  // -> step 1
  __builtin_amdgcn_sched_barrier(0);
  floatx4 scv0 = *(const floatx4*)sptr;
  floatx4 scv1 = *(const floatx4*)(sptr + 64);
  sptr += N_DIM;
  __builtin_amdgcn_sched_barrier(0);
  uintx4 qa[2], qb[2];
  qa[0] = *(const uintx4*)qptr;
  qb[0] = *(const uintx4*)(qptr + 64);
  qptr += 4 * (size_t)N_DIM;
  qa[1] = *(const uintx4*)qptr;
  qb[1] = *(const uintx4*)(qptr + 64);
  qptr += 4 * (size_t)N_DIM;  // -> step 2
  __builtin_amdgcn_sched_barrier(0);

  floatx4 scn0 = scv0, scn1 = scv1;

  for (int g = 0; g < GROUPS; ++g) {
    uint32_t s2b[8];
#pragma unroll
    for (int d = 0; d < 4; ++d) {
      unsigned short sb0 = bc<unsigned short>((_Float16)scv0[d]);  // exact
      uint32_t u0 = (uint32_t)sb0;
      s2b[d] = u0 | (u0 << 16);  // fp16x2 splat
      unsigned short sb1 = bc<unsigned short>((_Float16)scv1[d]);
      uint32_t u1 = (uint32_t)sb1;
      s2b[4 + d] = u1 | (u1 << 16);
    }
#pragma unroll
    for (int tt = 0; tt < 4; ++tt) {
      const int j = g * 4 + tt;
      const int pb = tt & 1;   // parity of j (g*4 even) — compile-time
      // Wait: everything except the 2 newest (the q pair issued last
      // iter) must retire — in particular this iter's S(j) stages.
      // Robust: S(j) is ALWAYS followed by >=2 younger ops.
      asm volatile("s_waitcnt vmcnt(2)" ::: "memory");
      __builtin_amdgcn_sched_barrier(0);
      // A fragments from OWN buffer: conflict-free ds_read_b128
      const _Float16* rb = pb ? myb1 : myb0;
      halfx8 afr[4];
#pragma unroll
      for (int mf = 0; mf < 4; ++mf)
        afr[mf] = *(const halfx8*)(rb + mf * 512 + l * 8);
      // compute: 8 dequant columns x 4 m-fragments = 32 MFMA
#pragma unroll
      for (int d = 0; d < 4; ++d) {
        halfx8 b = dequant8(qa[pb][d], s2b[d]);
#pragma unroll
        for (int mf = 0; mf < 4; ++mf)
          acc[mf][d] = __builtin_amdgcn_mfma_f32_16x16x32_f16(afr[mf], b,
                                                              acc[mf][d], 0, 0, 0);
      }
#pragma unroll
      for (int d = 0; d < 4; ++d) {
        halfx8 b = dequant8(qb[pb][d], s2b[4 + d]);
#pragma unroll
        for (int mf = 0; mf < 4; ++mf)
          acc[mf][4 + d] = __builtin_amdgcn_mfma_f32_16x16x32_f16(afr[mf], b,
                                                                  acc[mf][4 + d], 0, 0, 0);
      }
      __builtin_amdgcn_sched_barrier(0);
      // stage S(j+1) into the other private buffer (read next iter after
      // vmcnt(2); at the tail the address is clamped — restaged data is
      // never read)
      _Float16* wb = pb ? myb0 : myb1;
#pragma unroll
      for (int c = 0; c < 4; ++c) stage16(asrc + c * 512, wb + c * 512);
      asrc += (j + 2 < STEPS) ? 2048 : 0;
      if (tt == 0) {  // scales for group g+1 (issued before q -> q stays newest)
        __builtin_amdgcn_sched_barrier(0);
        scn0 = *(const floatx4*)sptr;
        scn1 = *(const floatx4*)(sptr + 64);
        sptr += (g + 1 < GROUPS) ? N_DIM : 0;
      }
      __builtin_amdgcn_sched_barrier(0);
      // q for step j+2 into just-consumed slot (clamped at tail; count kept)
      qa[pb] = *(const uintx4*)qptr;
      qb[pb] = *(const uintx4*)(qptr + 64);
      qptr += (j + 3 < STEPS) ? 4 * (size_t)N_DIM : (size_t)0;
      __builtin_amdgcn_sched_barrier(0);
    }
    scv0 = scn0;
    scv1 = scn1;
  }

  // Epilogue. row = 4*l4 + r (+16*mf); fragment d at (mf,r,h) covers
  // n = nbW + 64*h + 4*(l&15) + d -> 4 consecutive n. FP32 partials (proven).
  if (SPLIT) {
    float* pbase = part + (size_t)blockIdx.y * ((size_t)M_DIM * N_DIM);
#pragma unroll
    for (int h = 0; h < 2; ++h) {
      const int nc = ncol + 64 * h;
#pragma unroll
      for (int mf = 0; mf < 4; ++mf) {
#pragma unroll
        for (int r = 0; r < 4; ++r) {
          const int m = mf * 16 + l4 * 4 + r;
          floatx4 v = {acc[mf][4 * h + 0][r], acc[mf][4 * h + 1][r],
                       acc[mf][4 * h + 2][r], acc[mf][4 * h + 3][r]};
          *(floatx4*)(pbase + (size_t)m * N_DIM + nc) = v;
        }
      }
    }
  } else {
#pragma unroll
    for (int h = 0; h < 2; ++h) {
      const int nc = ncol + 64 * h;
      floatx4 bb = *(const floatx4*)(bias + nc);
#pragma unroll
      for (int mf = 0; mf < 4; ++mf) {
#pragma unroll
        for (int r = 0; r < 4; ++r) {
          const int m = mf * 16 + l4 * 4 + r;
          floatx4 v = {acc[mf][4 * h + 0][r] + bb.x, acc[mf][4 * h + 1][r] + bb.y,
                       acc[mf][4 * h + 2][r] + bb.z, acc[mf][4 * h + 3][r] + bb.w};
          *(floatx4*)(out + (size_t)m * N_DIM + nc) = v;
        }
      }
    }
  }
}

// Fallback (no workspace): register kernel, raw fp32 A, full K, 1 wave.
__global__ __launch_bounds__(64, 2) void wq_reg(
    const float* __restrict__ A, const int* __restrict__ qweight,
    const float* __restrict__ scales, const float* __restrict__ bias,
    float* __restrict__ out) {
  constexpr int KSLICE = K_DIM;
  constexpr int STEPS = KSLICE / 32;
  constexpr int GROUPS = KSLICE / QGROUP;
  const int l = (int)threadIdx.x & 63;
  const int l15 = l & 15;
  const int l4 = l >> 4;
  const int nb = (int)blockIdx.x * 128;
  const int ncol = nb + 4 * l15;
  const int* qptr = qweight + (size_t)l4 * N_DIM + ncol;
  const float* sptr = scales + ncol;
  const float* araw = A + (size_t)l15 * K_DIM + 8 * l4;

  floatx4 acc[4][8];
#pragma unroll
  for (int i = 0; i < 4; ++i)
#pragma unroll
    for (int j = 0; j < 8; ++j) acc[i][j] = (floatx4)(0.0f);

  uintx4 q0a = *(const uintx4*)qptr;
  uintx4 q0b = *(const uintx4*)(qptr + 64);
  qptr += 4 * (size_t)N_DIM;
  uintx4 q1a = *(const uintx4*)qptr;
  uintx4 q1b = *(const uintx4*)(qptr + 64);
  qptr += 4 * (size_t)N_DIM;
  floatx4 scv0 = *(const floatx4*)sptr;
  floatx4 scv1 = *(const floatx4*)(sptr + 64);
  sptr += N_DIM;

  for (int g = 0; g < GROUPS; ++g) {
    uint32_t s2b[8];
#pragma unroll
    for (int d = 0; d < 4; ++d) {
      unsigned short sb0 = bc<unsigned short>((_Float16)scv0[d]);
      uint32_t u0 = (uint32_t)sb0;
      s2b[d] = u0 | (u0 << 16);
      unsigned short sb1 = bc<unsigned short>((_Float16)scv1[d]);
      uint32_t u1 = (uint32_t)sb1;
      s2b[4 + d] = u1 | (u1 << 16);
    }
    floatx4 scn0 = scv0, scn1 = scv1;
    if (g + 1 < GROUPS) {
      scn0 = *(const floatx4*)sptr;
      scn1 = *(const floatx4*)(sptr + 64);
    }
    sptr += N_DIM;
#pragma unroll
    for (int tt = 0; tt < 4; ++tt) {
      const int t = g * 4 + tt;
      halfx8 afr[4];
#pragma unroll
      for (int mf = 0; mf < 4; ++mf) {
        const float* s0 = araw + (size_t)mf * 16 * K_DIM + (size_t)t * 32;
        floatx4 a0 = *(const floatx4*)s0;
        floatx4 a1 = *(const floatx4*)(s0 + 4);
        afr[mf][0] = (_Float16)a0[0]; afr[mf][1] = (_Float16)a1[0];
        afr[mf][2] = (_Float16)a0[1]; afr[mf][3] = (_Float16)a1[1];
        afr[mf][4] = (_Float16)a0[2]; afr[mf][5] = (_Float16)a1[2];
        afr[mf][6] = (_Float16)a0[3]; afr[mf][7] = (_Float16)a1[3];
      }
      uintx4 qna = q1a, qnb = q1b;
      if (t + 2 < STEPS) {
        qna = *(const uintx4*)qptr;
        qnb = *(const uintx4*)(qptr + 64);
      }
      qptr += 4 * (size_t)N_DIM;
#pragma unroll
      for (int d = 0; d < 4; ++d) {
        halfx8 b = dequant8(q0a[d], s2b[d]);
#pragma unroll
        for (int mf = 0; mf < 4; ++mf)
          acc[mf][d] = __builtin_amdgcn_mfma_f32_16x16x32_f16(afr[mf], b,
                                                              acc[mf][d], 0, 0, 0);
      }
#pragma unroll
      for (int d = 0; d < 4; ++d) {
        halfx8 b = dequant8(q0b[d], s2b[4 + d]);
#pragma unroll
        for (int mf = 0; mf < 4; ++mf)
          acc[mf][4 + d] = __builtin_amdgcn_mfma_f32_16x16x32_f16(afr[mf], b,
                                                                  acc[mf][4 + d], 0, 0, 0);
      }
      q0a = q1a; q0b = q1b;
      q1a = qna; q1b = qnb;
    }
    scv0 = scn0;
    scv1 = scn1;
  }
#pragma unroll
  for (int h = 0; h < 2; ++h) {
    const int nc = ncol + 64 * h;
    floatx4 bb = *(const floatx4*)(bias + nc);
#pragma unroll
    for (int mf = 0; mf < 4; ++mf) {
#pragma unroll
      for (int r = 0; r < 4; ++r) {
        const int m = mf * 16 + l4 * 4 + r;
        floatx4 v = {acc[mf][4 * h + 0][r] + bb.x, acc[mf][4 * h + 1][r] + bb.y,
                     acc[mf][4 * h + 2][r] + bb.z, acc[mf][4 * h + 3][r] + bb.w};
        *(floatx4*)(out + (size_t)m * N_DIM + nc) = v;
      }
    }
  }
}

// Sum KS fp32 partials, add fp32 bias, emit fp32.
template <int KS>
__global__ __launch_bounds__(256) void wq_reduce(const float* __restrict__ part,
                                                 const float* __restrict__ bias,
                                                 float* __restrict__ out) {
  const int idx = (int)blockIdx.x * 256 + (int)threadIdx.x;
  const int m = idx / (N_DIM / 4);
  const int n = (idx - m * (N_DIM / 4)) * 4;
  floatx4 s = (floatx4)(0.0f);
#pragma unroll
  for (int p = 0; p < KS; ++p)
    s += *(const floatx4*)(part + ((size_t)p * M_DIM + m) * N_DIM + n);
  floatx4 bb = *(const floatx4*)(bias + n);
  s += bb;
  *(floatx4*)(out + (size_t)m * N_DIM + n) = s;
}

extern "C" void kernel_launch(void* const* d_in, const int* in_sizes, int n_in,
                              void* d_out, int out_size, void* d_ws, size_t ws_size,
                              hipStream_t stream) {
  const float* A = (const float*)d_in[0];
  const int* qw = (const int*)d_in[1];
  const float* sc = (const float*)d_in[2];
  const float* bi = (const float*)d_in[3];
  float* out = (float*)d_out;

  char* ws = (char*)d_ws;
  const size_t packB = (size_t)M_DIM * K_DIM * sizeof(_Float16);  // 1 MiB
  const size_t mnB = (size_t)M_DIM * N_DIM * sizeof(float);       // 7.34 MB
  _Float16* Apack = (_Float16*)ws;
  float* part = (float*)(ws + packB);

  const int nblk = N_DIM / 512;                // 56 (4-wave 512n blocks)
  const int rblk = (M_DIM * N_DIM / 4) / 256;  // 1792

  if (ws_size >= packB + 8 * mnB) {
    // (56, 8) = 448 blocks x 4 waves = 1792 waves = 7 waves/CU nominal
    pack_a<<<256, 256, 0, stream>>>(A, Apack);
    wq_pvt<K_DIM / 8, true><<<dim3(nblk, 8), 256, 0, stream>>>(
        Apack, qw, sc, bi, part, out);
    wq_reduce<8><<<rblk, 256, 0, stream>>>(part, bi, out);
  } else if (ws_size >= packB + 4 * mnB) {
    pack_a<<<256, 256, 0, stream>>>(A, Apack);
    wq_pvt<K_DIM / 4, true><<<dim3(nblk, 4), 256, 0, stream>>>(
        Apack, qw, sc, bi, part, out);
    wq_reduce<4><<<rblk, 256, 0, stream>>>(part, bi, out);
  } else if (ws_size >= packB + 2 * mnB) {
    pack_a<<<256, 256, 0, stream>>>(A, Apack);
    wq_pvt<K_DIM / 2, true><<<dim3(nblk, 2), 256, 0, stream>>>(
        Apack, qw, sc, bi, part, out);
    wq_reduce<2><<<rblk, 256, 0, stream>>>(part, bi, out);
  } else if (ws_size >= packB) {
    pack_a<<<256, 256, 0, stream>>>(A, Apack);
    wq_pvt<K_DIM, false><<<dim3(nblk, 1), 256, 0, stream>>>(
        Apack, qw, sc, bi, part, out);
  } else {
    wq_reg<<<dim3(N_DIM / 128, 1), 64, 0, stream>>>(A, qw, sc, bi, out);
  }
}